// Round 4
// baseline (484.250 us; speedup 1.0000x reference)
//
#include <hip/hip_runtime.h>
#include <hip/hip_bf16.h>

#define D_MODEL 1024
#define N_HEADS 16
#define DK 64
#define B_SZ 4
#define T_SEQ 2048
#define M_ROWS (B_SZ * T_SEQ)   // 8192
#define QK_SCALE_LOG2 0.18033688f   // 0.125 * log2(e)

typedef short bf16x8 __attribute__((ext_vector_type(8)));
typedef float f32x4  __attribute__((ext_vector_type(4)));

__device__ inline unsigned short f32_to_bf16(float f) {
    union { float f; unsigned int u; } v; v.f = f;
    unsigned int r = v.u + 0x7fff + ((v.u >> 16) & 1);   // RNE
    return (unsigned short)(r >> 16);
}
__device__ inline float bf16_to_f32(unsigned short h) {
    union { unsigned int u; float f; } v; v.u = ((unsigned int)h) << 16;
    return v.f;
}
__device__ inline unsigned int pack_bf16x2(float a, float b) {
    __hip_bfloat162 t = __float22bfloat162_rn(make_float2(a, b));
    union { __hip_bfloat162 v; unsigned int u; } c; c.v = t;
    return c.u;   // low 16 = a
}

// ---------------------------------------------------------------------------
// Split fp32 -> (hi, lo) bf16 planes.  a ~= hi + lo with ~2^-18 rel residual.
// ---------------------------------------------------------------------------
__global__ __launch_bounds__(256) void split_bf16(
    const float* __restrict__ src, unsigned short* __restrict__ hi,
    unsigned short* __restrict__ lo, int n)
{
    for (int i = (blockIdx.x * 256 + threadIdx.x) * 4; i < n;
         i += gridDim.x * 256 * 4) {
        float4 v = *(const float4*)(src + i);
        ushort4 h, l;
        h.x = f32_to_bf16(v.x); l.x = f32_to_bf16(v.x - bf16_to_f32(h.x));
        h.y = f32_to_bf16(v.y); l.y = f32_to_bf16(v.y - bf16_to_f32(h.y));
        h.z = f32_to_bf16(v.z); l.z = f32_to_bf16(v.z - bf16_to_f32(h.z));
        h.w = f32_to_bf16(v.w); l.w = f32_to_bf16(v.w - bf16_to_f32(h.w));
        *(ushort4*)(hi + i) = h;
        *(ushort4*)(lo + i) = l;
    }
}

// ---------------------------------------------------------------------------
// Split-bf16 NT GEMM (unchanged from R3): 3 MFMAs per frag pair.
// ---------------------------------------------------------------------------
template <typename OutT>
__global__ __launch_bounds__(256) void gemm_split_nt(
    const unsigned short* __restrict__ Ah, const unsigned short* __restrict__ Al,
    const unsigned short* __restrict__ Bh, const unsigned short* __restrict__ Bl,
    OutT* __restrict__ C, int M, int N, int K)
{
    __shared__ __align__(16) unsigned short sA_h[128 * 32];
    __shared__ __align__(16) unsigned short sA_l[128 * 32];
    __shared__ __align__(16) unsigned short sB_h[128 * 32];
    __shared__ __align__(16) unsigned short sB_l[128 * 32];

    const int t    = threadIdx.x;
    const int wave = t >> 6;
    const int lane = t & 63;
    const int l15  = lane & 15;
    const int quad = lane >> 4;
    const int m0   = blockIdx.y * 128;
    const int n0   = blockIdx.x * 128;

    const unsigned short* gplane = wave == 0 ? Ah : wave == 1 ? Al
                                 : wave == 2 ? Bh : Bl;
    unsigned short* lplane = wave == 0 ? sA_h : wave == 1 ? sA_l
                           : wave == 2 ? sB_h : sB_l;
    const int row0   = (wave < 2) ? m0 : n0;
    const int srow   = lane >> 2;
    const int schunk = lane & 3;
    const unsigned short* gbase =
        gplane + (size_t)(row0 + srow) * K + schunk * 8;

    f32x4 acc[4][4];
#pragma unroll
    for (int i = 0; i < 4; ++i)
#pragma unroll
        for (int j = 0; j < 4; ++j) acc[i][j] = (f32x4){0.f, 0.f, 0.f, 0.f};

    const int wr = (wave >> 1) * 64;
    const int wc = (wave & 1) * 64;

    for (int k0 = 0; k0 < K; k0 += 32) {
#pragma unroll
        for (int i = 0; i < 8; ++i) {
            __builtin_amdgcn_global_load_lds(
                (const __attribute__((address_space(1))) unsigned int*)
                    (gbase + k0 + (size_t)i * 16 * K),
                (__attribute__((address_space(3))) unsigned int*)
                    (lplane + i * 512),
                16, 0, 0);
        }
        __syncthreads();

        bf16x8 a_h[4], a_l[4], b_h[4], b_l[4];
#pragma unroll
        for (int f = 0; f < 4; ++f) {
            const int ar = wr + f * 16 + l15;
            a_h[f] = *(const bf16x8*)&sA_h[ar * 32 + quad * 8];
            a_l[f] = *(const bf16x8*)&sA_l[ar * 32 + quad * 8];
            const int br = wc + f * 16 + l15;
            b_h[f] = *(const bf16x8*)&sB_h[br * 32 + quad * 8];
            b_l[f] = *(const bf16x8*)&sB_l[br * 32 + quad * 8];
        }
#pragma unroll
        for (int mi = 0; mi < 4; ++mi)
#pragma unroll
            for (int ni = 0; ni < 4; ++ni) {
                acc[mi][ni] = __builtin_amdgcn_mfma_f32_16x16x32_bf16(
                    a_h[mi], b_h[ni], acc[mi][ni], 0, 0, 0);
                acc[mi][ni] = __builtin_amdgcn_mfma_f32_16x16x32_bf16(
                    a_h[mi], b_l[ni], acc[mi][ni], 0, 0, 0);
                acc[mi][ni] = __builtin_amdgcn_mfma_f32_16x16x32_bf16(
                    a_l[mi], b_h[ni], acc[mi][ni], 0, 0, 0);
            }
        __syncthreads();
    }

#pragma unroll
    for (int mi = 0; mi < 4; ++mi)
#pragma unroll
        for (int r = 0; r < 4; ++r) {
            OutT* crow = C + (size_t)(m0 + wr + mi * 16 + quad * 4 + r) * N
                         + n0 + wc + l15;
#pragma unroll
            for (int ni = 0; ni < 4; ++ni) {
                const float v = acc[mi][ni][r];
                if constexpr (sizeof(OutT) == 2)
                    crow[ni * 16] = (OutT)f32_to_bf16(v);
                else
                    crow[ni * 16] = (OutT)v;
            }
        }
}

// ---------------------------------------------------------------------------
// Build V^T per (b,h): VT[b,h,dk,t] (bf16)
// ---------------------------------------------------------------------------
__global__ __launch_bounds__(256) void prep_vt(
    const unsigned short* __restrict__ qkvb, unsigned short* __restrict__ vt)
{
    __shared__ unsigned short VT_s[64][264];
    const int t  = threadIdx.x;
    const int b  = blockIdx.z, h = blockIdx.y;
    const int t0 = blockIdx.x * 256;
    const unsigned short* vb = qkvb + (size_t)(b * T_SEQ) * (3 * D_MODEL)
                               + 2 * D_MODEL + h * DK;
#pragma unroll
    for (int it = 0; it < 16; ++it) {
        const int trow = (t >> 4) + it * 16;
        const int dk0  = (t & 15) * 4;
        ushort4 v = *(const ushort4*)(vb + (size_t)(t0 + trow) * (3 * D_MODEL) + dk0);
        VT_s[dk0 + 0][trow] = v.x; VT_s[dk0 + 1][trow] = v.y;
        VT_s[dk0 + 2][trow] = v.z; VT_s[dk0 + 3][trow] = v.w;
    }
    __syncthreads();
    const int row = t >> 2;
    const int c0  = (t & 3) * 64;
    unsigned short* dst = vt + ((size_t)(b * N_HEADS + h) * DK + row) * T_SEQ + t0 + c0;
#pragma unroll
    for (int i = 0; i < 8; ++i)
        *(uint4*)(dst + i * 8) = *(const uint4*)&VT_s[row][c0 + i * 8];
}

// ---------------------------------------------------------------------------
// MFMA flash attention, R4: S computed transposed (S^T = K*Q^T via operand
// swap) so each thread's D regs hold 4 consecutive kv for one q -> packed
// b64 P-stores. 128-kv staging halves barriers. Per-lane q row-sum (q=l15),
// reduced across quads once at the end.
// ---------------------------------------------------------------------------
__global__ __launch_bounds__(256) void attn_mfma(
    const unsigned short* __restrict__ qkvb,   // [B,T,3D] bf16
    const unsigned short* __restrict__ vt,     // [B,H,DK,T] bf16
    unsigned short* __restrict__ ohi,          // [B,T,D] bf16 hi
    unsigned short* __restrict__ olo)          // [B,T,D] bf16 lo
{
    __shared__ __align__(16) unsigned short Ksw[128 * 64];    // [kv][dk] swizzled
    __shared__ __align__(16) unsigned short Vsw[64 * 128];    // [dk][kv] swizzled
    __shared__ __align__(16) unsigned short Psw[4][16 * 64];  // per-wave [q][kv]

    const int t    = threadIdx.x;
    const int wave = t >> 6;
    const int lane = t & 63;
    const int l15  = t & 15;
    const int quad = lane >> 4;
    const int swz  = l15 & 7;      // row-XOR for all MFMA-side LDS reads

    const int b  = blockIdx.z;
    const int h  = blockIdx.y;
    const int q0 = blockIdx.x * 64;

    // Q A/B frags: loop-invariant, direct from global
    const unsigned short* qrow =
        qkvb + ((size_t)(b * T_SEQ) + q0 + wave * 16 + l15) * (3 * D_MODEL) + h * DK;
    const bf16x8 qa0 = *(const bf16x8*)(qrow + quad * 8);
    const bf16x8 qa1 = *(const bf16x8*)(qrow + 32 + quad * 8);

    f32x4 O[4];
#pragma unroll
    for (int nf = 0; nf < 4; ++nf) O[nf] = (f32x4){0.f, 0.f, 0.f, 0.f};
    float lsum = 0.f;   // row sum for q = l15 (+wave*16)

    const unsigned short* kbase =
        qkvb + (size_t)(b * T_SEQ) * (3 * D_MODEL) + D_MODEL + h * DK;
    const unsigned short* vbase = vt + (size_t)(b * N_HEADS + h) * DK * T_SEQ;

    for (int c0 = 0; c0 < T_SEQ; c0 += 128) {
        // stage K [128 kv][64 dk] + V^T [64 dk][128 kv], XOR-swizzled 16B chunks
        int f = t;
#pragma unroll
        for (int it = 0; it < 4; ++it, f += 256) {
            const int kr = f >> 3, kc = f & 7;
            *(uint4*)&Ksw[kr * 64 + ((kc ^ (kr & 7)) * 8)] =
                *(const uint4*)(kbase + (size_t)(c0 + kr) * (3 * D_MODEL) + kc * 8);
            const int vr = f >> 4, vc = f & 15;
            *(uint4*)&Vsw[vr * 128 + ((((vc & 7) ^ (vr & 7)) | (vc & 8)) * 8)] =
                *(const uint4*)(vbase + (size_t)vr * T_SEQ + c0 + vc * 8);
        }
        __syncthreads();

#pragma unroll
        for (int half = 0; half < 2; ++half) {
            // S^T = K * Q^T : A = K-frag (m=kv), B = Q-frag (n=q)
            f32x4 S[4];
#pragma unroll
            for (int nf = 0; nf < 4; ++nf) S[nf] = (f32x4){0.f, 0.f, 0.f, 0.f};
#pragma unroll
            for (int ks = 0; ks < 2; ++ks) {
                const bf16x8 qb = ks ? qa1 : qa0;
                const int ch = ks * 4 + quad;
#pragma unroll
                for (int nf = 0; nf < 4; ++nf) {
                    const int row = half * 64 + nf * 16 + l15;   // kv
                    const bf16x8 ka = *(const bf16x8*)&Ksw[row * 64 + ((ch ^ swz) * 8)];
                    S[nf] = __builtin_amdgcn_mfma_f32_16x16x32_bf16(ka, qb, S[nf], 0, 0, 0);
                }
            }

            // p = exp2(s*scale); packed b64 stores into per-wave P
#pragma unroll
            for (int nf = 0; nf < 4; ++nf) {
                const float p0 = __builtin_amdgcn_exp2f(S[nf][0] * QK_SCALE_LOG2);
                const float p1 = __builtin_amdgcn_exp2f(S[nf][1] * QK_SCALE_LOG2);
                const float p2 = __builtin_amdgcn_exp2f(S[nf][2] * QK_SCALE_LOG2);
                const float p3 = __builtin_amdgcn_exp2f(S[nf][3] * QK_SCALE_LOG2);
                lsum += (p0 + p1) + (p2 + p3);
                uint2 u;
                u.x = pack_bf16x2(p0, p1);
                u.y = pack_bf16x2(p2, p3);
                const int chunk = nf * 2 + (quad >> 1);
                *(uint2*)&Psw[wave][l15 * 64 + ((chunk ^ swz) * 8) + (quad & 1) * 4] = u;
            }

            // O += P * V^T  (A = P (m=q), B = V^T (n=dk))
#pragma unroll
            for (int ks = 0; ks < 2; ++ks) {
                const int ch = ks * 4 + quad;
                const bf16x8 ap = *(const bf16x8*)&Psw[wave][l15 * 64 + ((ch ^ swz) * 8)];
                const int vch = half * 8 + ks * 4 + quad;
                const int vsw = (((vch & 7) ^ swz) | (vch & 8)) * 8;
#pragma unroll
                for (int nf = 0; nf < 4; ++nf) {
                    const int row = nf * 16 + l15;               // dk
                    const bf16x8 bv = *(const bf16x8*)&Vsw[row * 128 + vsw];
                    O[nf] = __builtin_amdgcn_mfma_f32_16x16x32_bf16(ap, bv, O[nf], 0, 0, 0);
                }
            }
        }
        __syncthreads();
    }

    // finish row sums: lanes {l15, l15+16, l15+32, l15+48} share q=l15
    lsum += __shfl_xor(lsum, 16);
    lsum += __shfl_xor(lsum, 32);
    // O rows are q = quad*4+r -> fetch that q's sum from lane quad*4+r
    float invl[4];
#pragma unroll
    for (int r = 0; r < 4; ++r) invl[r] = 1.0f / __shfl(lsum, quad * 4 + r);

#pragma unroll
    for (int nf = 0; nf < 4; ++nf)
#pragma unroll
        for (int r = 0; r < 4; ++r) {
            const float v = O[nf][r] * invl[r];
            const size_t idx =
                ((size_t)(b * T_SEQ) + q0 + wave * 16 + quad * 4 + r) * D_MODEL
                + h * DK + nf * 16 + l15;
            const unsigned short hh = f32_to_bf16(v);
            ohi[idx] = hh;
            olo[idx] = f32_to_bf16(v - bf16_to_f32(hh));
        }
}

// ---------------------------------------------------------------------------
extern "C" void kernel_launch(void* const* d_in, const int* in_sizes, int n_in,
                              void* d_out, int out_size, void* d_ws, size_t ws_size,
                              hipStream_t stream)
{
    const float* x      = (const float*)d_in[0];
    const float* W_qkv  = (const float*)d_in[1];
    const float* W_proj = (const float*)d_in[2];
    float* out = (float*)d_out;

    const size_t XN = (size_t)M_ROWS * D_MODEL;
    const size_t WQ = (size_t)3 * D_MODEL * D_MODEL;
    const size_t WP = (size_t)D_MODEL * D_MODEL;
    unsigned short* xh   = (unsigned short*)d_ws;
    unsigned short* xl   = xh + XN;
    unsigned short* wqh  = xl + XN;
    unsigned short* wql  = wqh + WQ;
    unsigned short* wph  = wql + WQ;
    unsigned short* wpl  = wph + WP;
    unsigned short* qkvb = wpl + WP;
    unsigned short* vtb  = qkvb + (size_t)M_ROWS * 3 * D_MODEL;
    unsigned short* ahi  = xh;   // overlay (x planes dead after QKV GEMM)
    unsigned short* alo  = xl;

    dim3 blk(256);
    split_bf16<<<512, blk, 0, stream>>>(x, xh, xl, (int)XN);
    split_bf16<<<256, blk, 0, stream>>>(W_qkv, wqh, wql, (int)WQ);
    split_bf16<<<128, blk, 0, stream>>>(W_proj, wph, wpl, (int)WP);

    gemm_split_nt<unsigned short>
        <<<dim3(3 * D_MODEL / 128, M_ROWS / 128), blk, 0, stream>>>(
        xh, xl, wqh, wql, qkvb, M_ROWS, 3 * D_MODEL, D_MODEL);

    prep_vt<<<dim3(T_SEQ / 256, N_HEADS, B_SZ), blk, 0, stream>>>(qkvb, vtb);
    attn_mfma<<<dim3(T_SEQ / 64, N_HEADS, B_SZ), blk, 0, stream>>>(
        qkvb, vtb, ahi, alo);

    gemm_split_nt<float>
        <<<dim3(D_MODEL / 128, M_ROWS / 128), blk, 0, stream>>>(
        ahi, alo, wph, wpl, out, M_ROWS, D_MODEL, D_MODEL);
}

// Round 5
// 385.287 us; speedup vs baseline: 1.2569x; 1.2569x over previous
//
#include <hip/hip_runtime.h>
#include <hip/hip_bf16.h>

#define D_MODEL 1024
#define N_HEADS 16
#define DK 64
#define B_SZ 4
#define T_SEQ 2048
#define M_ROWS (B_SZ * T_SEQ)   // 8192
#define QK_SCALE_LOG2 0.18033688f   // 0.125 * log2(e)

typedef short bf16x8 __attribute__((ext_vector_type(8)));
typedef float f32x4  __attribute__((ext_vector_type(4)));

__device__ inline unsigned short f32_to_bf16(float f) {
    union { float f; unsigned int u; } v; v.f = f;
    unsigned int r = v.u + 0x7fff + ((v.u >> 16) & 1);   // RNE
    return (unsigned short)(r >> 16);
}
__device__ inline float bf16_to_f32(unsigned short h) {
    union { unsigned int u; float f; } v; v.u = ((unsigned int)h) << 16;
    return v.f;
}
__device__ inline unsigned int pack_bf16x2(float a, float b) {
    __hip_bfloat162 t = __float22bfloat162_rn(make_float2(a, b));
    union { __hip_bfloat162 v; unsigned int u; } c; c.v = t;
    return c.u;   // low 16 = a
}

// ---------------------------------------------------------------------------
// Cast fp32 -> bf16 (RNE), vectorized.
// ---------------------------------------------------------------------------
__global__ __launch_bounds__(256) void cast_bf16(
    const float* __restrict__ src, unsigned short* __restrict__ dst, int n)
{
    for (int i = (blockIdx.x * 256 + threadIdx.x) * 4; i < n;
         i += gridDim.x * 256 * 4) {
        float4 v = *(const float4*)(src + i);
        ushort4 h;
        h.x = f32_to_bf16(v.x); h.y = f32_to_bf16(v.y);
        h.z = f32_to_bf16(v.z); h.w = f32_to_bf16(v.w);
        *(ushort4*)(dst + i) = h;
    }
}

// ---------------------------------------------------------------------------
// Split fp32 -> (hi, lo) bf16 planes (proj weights only).
// ---------------------------------------------------------------------------
__global__ __launch_bounds__(256) void split_bf16(
    const float* __restrict__ src, unsigned short* __restrict__ hi,
    unsigned short* __restrict__ lo, int n)
{
    for (int i = (blockIdx.x * 256 + threadIdx.x) * 4; i < n;
         i += gridDim.x * 256 * 4) {
        float4 v = *(const float4*)(src + i);
        ushort4 h, l;
        h.x = f32_to_bf16(v.x); l.x = f32_to_bf16(v.x - bf16_to_f32(h.x));
        h.y = f32_to_bf16(v.y); l.y = f32_to_bf16(v.y - bf16_to_f32(h.y));
        h.z = f32_to_bf16(v.z); l.z = f32_to_bf16(v.z - bf16_to_f32(h.z));
        h.w = f32_to_bf16(v.w); l.w = f32_to_bf16(v.w - bf16_to_f32(h.w));
        *(ushort4*)(hi + i) = h;
        *(ushort4*)(lo + i) = l;
    }
}

// ---------------------------------------------------------------------------
// Plain bf16 NT GEMM: C[M][N] = A[M][K] * B[N][K]^T, 1 MFMA per frag pair.
// 128x128 tile, BK=32, 4 waves (64x64 quadrant each), global_load_lds w=16.
// bf16 output (for qkv; rounded anyway so full split accuracy is wasted).
// ---------------------------------------------------------------------------
__global__ __launch_bounds__(256) void gemm_bf16_nt(
    const unsigned short* __restrict__ A, const unsigned short* __restrict__ B,
    unsigned short* __restrict__ C, int M, int N, int K)
{
    __shared__ __align__(16) unsigned short sA[128 * 32];
    __shared__ __align__(16) unsigned short sB[128 * 32];

    const int t    = threadIdx.x;
    const int wave = t >> 6;
    const int lane = t & 63;
    const int l15  = lane & 15;
    const int quad = lane >> 4;
    const int m0   = blockIdx.y * 128;
    const int n0   = blockIdx.x * 128;

    // staging: waves 0,1 -> A rows [wsub*64, +64); waves 2,3 -> B likewise
    const unsigned short* gplane = (wave < 2) ? A : B;
    unsigned short* lplane = (wave < 2) ? sA : sB;
    const int row0 = ((wave < 2) ? m0 : n0) + (wave & 1) * 64;
    const int lds0 = (wave & 1) * 2048;                    // elems
    const unsigned short* gbase =
        gplane + (size_t)(row0 + (lane >> 2)) * K + (lane & 3) * 8;

    f32x4 acc[4][4];
#pragma unroll
    for (int i = 0; i < 4; ++i)
#pragma unroll
        for (int j = 0; j < 4; ++j) acc[i][j] = (f32x4){0.f, 0.f, 0.f, 0.f};

    const int wr = (wave >> 1) * 64;
    const int wc = (wave & 1) * 64;

    for (int k0 = 0; k0 < K; k0 += 32) {
#pragma unroll
        for (int i = 0; i < 4; ++i) {
            __builtin_amdgcn_global_load_lds(
                (const __attribute__((address_space(1))) unsigned int*)
                    (gbase + k0 + (size_t)i * 16 * K),
                (__attribute__((address_space(3))) unsigned int*)
                    (lplane + lds0 + i * 512),
                16, 0, 0);
        }
        __syncthreads();

        bf16x8 a[4], b[4];
#pragma unroll
        for (int f = 0; f < 4; ++f) {
            a[f] = *(const bf16x8*)&sA[(wr + f * 16 + l15) * 32 + quad * 8];
            b[f] = *(const bf16x8*)&sB[(wc + f * 16 + l15) * 32 + quad * 8];
        }
#pragma unroll
        for (int mi = 0; mi < 4; ++mi)
#pragma unroll
            for (int ni = 0; ni < 4; ++ni)
                acc[mi][ni] = __builtin_amdgcn_mfma_f32_16x16x32_bf16(
                    a[mi], b[ni], acc[mi][ni], 0, 0, 0);
        __syncthreads();
    }

#pragma unroll
    for (int mi = 0; mi < 4; ++mi)
#pragma unroll
        for (int r = 0; r < 4; ++r) {
            unsigned short* crow =
                C + (size_t)(m0 + wr + mi * 16 + quad * 4 + r) * N + n0 + wc + l15;
#pragma unroll
            for (int ni = 0; ni < 4; ++ni)
                crow[ni * 16] = f32_to_bf16(acc[mi][ni][r]);
        }
}

// ---------------------------------------------------------------------------
// Split-bf16 NT GEMM (proj only): 3 MFMAs per frag pair, fp32 out.
// ---------------------------------------------------------------------------
__global__ __launch_bounds__(256) void gemm_split_nt(
    const unsigned short* __restrict__ Ah, const unsigned short* __restrict__ Al,
    const unsigned short* __restrict__ Bh, const unsigned short* __restrict__ Bl,
    float* __restrict__ C, int M, int N, int K)
{
    __shared__ __align__(16) unsigned short sA_h[128 * 32];
    __shared__ __align__(16) unsigned short sA_l[128 * 32];
    __shared__ __align__(16) unsigned short sB_h[128 * 32];
    __shared__ __align__(16) unsigned short sB_l[128 * 32];

    const int t    = threadIdx.x;
    const int wave = t >> 6;
    const int lane = t & 63;
    const int l15  = lane & 15;
    const int quad = lane >> 4;
    const int m0   = blockIdx.y * 128;
    const int n0   = blockIdx.x * 128;

    const unsigned short* gplane = wave == 0 ? Ah : wave == 1 ? Al
                                 : wave == 2 ? Bh : Bl;
    unsigned short* lplane = wave == 0 ? sA_h : wave == 1 ? sA_l
                           : wave == 2 ? sB_h : sB_l;
    const int row0 = (wave < 2) ? m0 : n0;
    const unsigned short* gbase =
        gplane + (size_t)(row0 + (lane >> 2)) * K + (lane & 3) * 8;

    f32x4 acc[4][4];
#pragma unroll
    for (int i = 0; i < 4; ++i)
#pragma unroll
        for (int j = 0; j < 4; ++j) acc[i][j] = (f32x4){0.f, 0.f, 0.f, 0.f};

    const int wr = (wave >> 1) * 64;
    const int wc = (wave & 1) * 64;

    for (int k0 = 0; k0 < K; k0 += 32) {
#pragma unroll
        for (int i = 0; i < 8; ++i) {
            __builtin_amdgcn_global_load_lds(
                (const __attribute__((address_space(1))) unsigned int*)
                    (gbase + k0 + (size_t)i * 16 * K),
                (__attribute__((address_space(3))) unsigned int*)
                    (lplane + i * 512),
                16, 0, 0);
        }
        __syncthreads();

        bf16x8 a_h[4], a_l[4], b_h[4], b_l[4];
#pragma unroll
        for (int f = 0; f < 4; ++f) {
            const int ar = wr + f * 16 + l15;
            a_h[f] = *(const bf16x8*)&sA_h[ar * 32 + quad * 8];
            a_l[f] = *(const bf16x8*)&sA_l[ar * 32 + quad * 8];
            const int br = wc + f * 16 + l15;
            b_h[f] = *(const bf16x8*)&sB_h[br * 32 + quad * 8];
            b_l[f] = *(const bf16x8*)&sB_l[br * 32 + quad * 8];
        }
#pragma unroll
        for (int mi = 0; mi < 4; ++mi)
#pragma unroll
            for (int ni = 0; ni < 4; ++ni) {
                acc[mi][ni] = __builtin_amdgcn_mfma_f32_16x16x32_bf16(
                    a_h[mi], b_h[ni], acc[mi][ni], 0, 0, 0);
                acc[mi][ni] = __builtin_amdgcn_mfma_f32_16x16x32_bf16(
                    a_h[mi], b_l[ni], acc[mi][ni], 0, 0, 0);
                acc[mi][ni] = __builtin_amdgcn_mfma_f32_16x16x32_bf16(
                    a_l[mi], b_h[ni], acc[mi][ni], 0, 0, 0);
            }
        __syncthreads();
    }

#pragma unroll
    for (int mi = 0; mi < 4; ++mi)
#pragma unroll
        for (int r = 0; r < 4; ++r) {
            float* crow = C + (size_t)(m0 + wr + mi * 16 + quad * 4 + r) * N
                          + n0 + wc + l15;
#pragma unroll
            for (int ni = 0; ni < 4; ++ni)
                crow[ni * 16] = acc[mi][ni][r];
        }
}

// ---------------------------------------------------------------------------
// Build V^T per (b,h): VT[b,h,dk,t] (bf16)
// ---------------------------------------------------------------------------
__global__ __launch_bounds__(256) void prep_vt(
    const unsigned short* __restrict__ qkvb, unsigned short* __restrict__ vt)
{
    __shared__ unsigned short VT_s[64][264];
    const int t  = threadIdx.x;
    const int b  = blockIdx.z, h = blockIdx.y;
    const int t0 = blockIdx.x * 256;
    const unsigned short* vb = qkvb + (size_t)(b * T_SEQ) * (3 * D_MODEL)
                               + 2 * D_MODEL + h * DK;
#pragma unroll
    for (int it = 0; it < 16; ++it) {
        const int trow = (t >> 4) + it * 16;
        const int dk0  = (t & 15) * 4;
        ushort4 v = *(const ushort4*)(vb + (size_t)(t0 + trow) * (3 * D_MODEL) + dk0);
        VT_s[dk0 + 0][trow] = v.x; VT_s[dk0 + 1][trow] = v.y;
        VT_s[dk0 + 2][trow] = v.z; VT_s[dk0 + 3][trow] = v.w;
    }
    __syncthreads();
    const int row = t >> 2;
    const int c0  = (t & 3) * 64;
    unsigned short* dst = vt + ((size_t)(b * N_HEADS + h) * DK + row) * T_SEQ + t0 + c0;
#pragma unroll
    for (int i = 0; i < 8; ++i)
        *(uint4*)(dst + i * 8) = *(const uint4*)&VT_s[row][c0 + i * 8];
}

// ---------------------------------------------------------------------------
// MFMA flash attention (identical to R4).
// ---------------------------------------------------------------------------
__global__ __launch_bounds__(256) void attn_mfma(
    const unsigned short* __restrict__ qkvb,   // [B,T,3D] bf16
    const unsigned short* __restrict__ vt,     // [B,H,DK,T] bf16
    unsigned short* __restrict__ ohi,          // [B,T,D] bf16 hi
    unsigned short* __restrict__ olo)          // [B,T,D] bf16 lo
{
    __shared__ __align__(16) unsigned short Ksw[128 * 64];
    __shared__ __align__(16) unsigned short Vsw[64 * 128];
    __shared__ __align__(16) unsigned short Psw[4][16 * 64];

    const int t    = threadIdx.x;
    const int wave = t >> 6;
    const int lane = t & 63;
    const int l15  = t & 15;
    const int quad = lane >> 4;
    const int swz  = l15 & 7;

    const int b  = blockIdx.z;
    const int h  = blockIdx.y;
    const int q0 = blockIdx.x * 64;

    const unsigned short* qrow =
        qkvb + ((size_t)(b * T_SEQ) + q0 + wave * 16 + l15) * (3 * D_MODEL) + h * DK;
    const bf16x8 qa0 = *(const bf16x8*)(qrow + quad * 8);
    const bf16x8 qa1 = *(const bf16x8*)(qrow + 32 + quad * 8);

    f32x4 O[4];
#pragma unroll
    for (int nf = 0; nf < 4; ++nf) O[nf] = (f32x4){0.f, 0.f, 0.f, 0.f};
    float lsum = 0.f;

    const unsigned short* kbase =
        qkvb + (size_t)(b * T_SEQ) * (3 * D_MODEL) + D_MODEL + h * DK;
    const unsigned short* vbase = vt + (size_t)(b * N_HEADS + h) * DK * T_SEQ;

    for (int c0 = 0; c0 < T_SEQ; c0 += 128) {
        int f = t;
#pragma unroll
        for (int it = 0; it < 4; ++it, f += 256) {
            const int kr = f >> 3, kc = f & 7;
            *(uint4*)&Ksw[kr * 64 + ((kc ^ (kr & 7)) * 8)] =
                *(const uint4*)(kbase + (size_t)(c0 + kr) * (3 * D_MODEL) + kc * 8);
            const int vr = f >> 4, vc = f & 15;
            *(uint4*)&Vsw[vr * 128 + ((((vc & 7) ^ (vr & 7)) | (vc & 8)) * 8)] =
                *(const uint4*)(vbase + (size_t)vr * T_SEQ + c0 + vc * 8);
        }
        __syncthreads();

#pragma unroll
        for (int half = 0; half < 2; ++half) {
            f32x4 S[4];
#pragma unroll
            for (int nf = 0; nf < 4; ++nf) S[nf] = (f32x4){0.f, 0.f, 0.f, 0.f};
#pragma unroll
            for (int ks = 0; ks < 2; ++ks) {
                const bf16x8 qb = ks ? qa1 : qa0;
                const int ch = ks * 4 + quad;
#pragma unroll
                for (int nf = 0; nf < 4; ++nf) {
                    const int row = half * 64 + nf * 16 + l15;
                    const bf16x8 ka = *(const bf16x8*)&Ksw[row * 64 + ((ch ^ swz) * 8)];
                    S[nf] = __builtin_amdgcn_mfma_f32_16x16x32_bf16(ka, qb, S[nf], 0, 0, 0);
                }
            }

#pragma unroll
            for (int nf = 0; nf < 4; ++nf) {
                const float p0 = __builtin_amdgcn_exp2f(S[nf][0] * QK_SCALE_LOG2);
                const float p1 = __builtin_amdgcn_exp2f(S[nf][1] * QK_SCALE_LOG2);
                const float p2 = __builtin_amdgcn_exp2f(S[nf][2] * QK_SCALE_LOG2);
                const float p3 = __builtin_amdgcn_exp2f(S[nf][3] * QK_SCALE_LOG2);
                lsum += (p0 + p1) + (p2 + p3);
                uint2 u;
                u.x = pack_bf16x2(p0, p1);
                u.y = pack_bf16x2(p2, p3);
                const int chunk = nf * 2 + (quad >> 1);
                *(uint2*)&Psw[wave][l15 * 64 + ((chunk ^ swz) * 8) + (quad & 1) * 4] = u;
            }

#pragma unroll
            for (int ks = 0; ks < 2; ++ks) {
                const int ch = ks * 4 + quad;
                const bf16x8 ap = *(const bf16x8*)&Psw[wave][l15 * 64 + ((ch ^ swz) * 8)];
                const int vch = half * 8 + ks * 4 + quad;
                const int vsw = (((vch & 7) ^ swz) | (vch & 8)) * 8;
#pragma unroll
                for (int nf = 0; nf < 4; ++nf) {
                    const int row = nf * 16 + l15;
                    const bf16x8 bv = *(const bf16x8*)&Vsw[row * 128 + vsw];
                    O[nf] = __builtin_amdgcn_mfma_f32_16x16x32_bf16(ap, bv, O[nf], 0, 0, 0);
                }
            }
        }
        __syncthreads();
    }

    lsum += __shfl_xor(lsum, 16);
    lsum += __shfl_xor(lsum, 32);
    float invl[4];
#pragma unroll
    for (int r = 0; r < 4; ++r) invl[r] = 1.0f / __shfl(lsum, quad * 4 + r);

#pragma unroll
    for (int nf = 0; nf < 4; ++nf)
#pragma unroll
        for (int r = 0; r < 4; ++r) {
            const float v = O[nf][r] * invl[r];
            const size_t idx =
                ((size_t)(b * T_SEQ) + q0 + wave * 16 + quad * 4 + r) * D_MODEL
                + h * DK + nf * 16 + l15;
            const unsigned short hh = f32_to_bf16(v);
            ohi[idx] = hh;
            olo[idx] = f32_to_bf16(v - bf16_to_f32(hh));
        }
}

// ---------------------------------------------------------------------------
extern "C" void kernel_launch(void* const* d_in, const int* in_sizes, int n_in,
                              void* d_out, int out_size, void* d_ws, size_t ws_size,
                              hipStream_t stream)
{
    const float* x      = (const float*)d_in[0];
    const float* W_qkv  = (const float*)d_in[1];
    const float* W_proj = (const float*)d_in[2];
    float* out = (float*)d_out;

    // workspace (ushort units), total ~111 MB (117.4 MB proven available):
    // xb dead after QKV GEMM -> attention hi plane overlays it.
    const size_t XN = (size_t)M_ROWS * D_MODEL;        // 8.4M
    const size_t WQ = (size_t)3 * D_MODEL * D_MODEL;   // 3.1M
    const size_t WP = (size_t)D_MODEL * D_MODEL;       // 1.0M
    unsigned short* xb   = (unsigned short*)d_ws;
    unsigned short* wqb  = xb + XN;
    unsigned short* wph  = wqb + WQ;
    unsigned short* wpl  = wph + WP;
    unsigned short* qkvb = wpl + WP;
    unsigned short* vtb  = qkvb + (size_t)M_ROWS * 3 * D_MODEL;
    unsigned short* alo  = vtb + (size_t)B_SZ * N_HEADS * DK * T_SEQ;
    unsigned short* ahi  = xb;   // overlay

    dim3 blk(256);
    cast_bf16<<<512, blk, 0, stream>>>(x, xb, (int)XN);
    cast_bf16<<<256, blk, 0, stream>>>(W_qkv, wqb, (int)WQ);
    split_bf16<<<128, blk, 0, stream>>>(W_proj, wph, wpl, (int)WP);

    gemm_bf16_nt<<<dim3(3 * D_MODEL / 128, M_ROWS / 128), blk, 0, stream>>>(
        xb, wqb, qkvb, M_ROWS, 3 * D_MODEL, D_MODEL);

    prep_vt<<<dim3(T_SEQ / 256, N_HEADS, B_SZ), blk, 0, stream>>>(qkvb, vtb);
    attn_mfma<<<dim3(T_SEQ / 64, N_HEADS, B_SZ), blk, 0, stream>>>(
        qkvb, vtb, ahi, alo);

    gemm_split_nt<<<dim3(D_MODEL / 128, M_ROWS / 128), blk, 0, stream>>>(
        ahi, alo, wph, wpl, out, M_ROWS, D_MODEL, D_MODEL);
}